// Round 3
// baseline (73.511 us; speedup 1.0000x reference)
//
#include <hip/hip_runtime.h>

// out[b,t,u] = y[b,t]*out[b,t-1,u] + x[b,t]*z[b,t,u], out[b,-1,u]=0
// in layout: [B][T][F] with F=1026: x=col0, y=col1, z=cols 2..1025
//
// Two-kernel chunked scan:
//  k_partial: per (b,chunk): zero-init recurrence over C rows -> Bc; chunk y-product -> A
//  k_final:   per (b,chunk): prologue scans A/Bc (c<chunk) for the incoming carry
//             (replaces the old standalone k_scan dispatch), then re-runs the chunk
//             seeded with the carry, streaming outputs with nontemporal stores.
// Input (134 MB) < L3 (256 MB), so k_final's re-read is mostly Infinity-Cache-hit.

#define BB 8
#define TT 4096
#define FF 1026
#define UU 1024

typedef float f2 __attribute__((ext_vector_type(2)));

template <int NC>
__global__ __launch_bounds__(256) void k_partial(const float* __restrict__ in,
                                                 float* __restrict__ A,
                                                 float* __restrict__ Bc) {
    constexpr int CC = TT / NC;
    constexpr int LOG2NC = (NC == 64) ? 6 : 5;
    int bid   = blockIdx.x;                 // BB*NC*2 blocks
    int s     = bid & 1;
    int chunk = (bid >> 1) & (NC - 1);
    int b     = bid >> (1 + LOG2NC);
    int u     = s * 512 + threadIdx.x * 2;

    const float* row = in + ((size_t)b * TT + (size_t)chunk * CC) * FF;
    float accx = 0.f, accy = 0.f, yprod = 1.f;
#pragma unroll 8
    for (int t = 0; t < CC; ++t) {
        f2 xy = *reinterpret_cast<const f2*>(row + (size_t)t * FF);
        f2 z  = *reinterpret_cast<const f2*>(row + (size_t)t * FF + 2 + u);
        accx  = fmaf(xy.y, accx, xy.x * z.x);
        accy  = fmaf(xy.y, accy, xy.x * z.y);
        yprod *= xy.y;
    }
    f2 o; o.x = accx; o.y = accy;
    *reinterpret_cast<f2*>(Bc + ((size_t)b * NC + chunk) * UU + u) = o;
    if (threadIdx.x == 0 && s == 0) A[b * NC + chunk] = yprod;
}

template <int NC>
__global__ __launch_bounds__(256) void k_final(const float* __restrict__ in,
                                               const float* __restrict__ A,
                                               const float* __restrict__ Bc,
                                               float* __restrict__ out) {
    constexpr int CC = TT / NC;
    constexpr int LOG2NC = (NC == 64) ? 6 : 5;
    int bid   = blockIdx.x;
    int s     = bid & 1;
    int chunk = (bid >> 1) & (NC - 1);
    int b     = bid >> (1 + LOG2NC);
    int u     = s * 512 + threadIdx.x * 2;

    // Prologue: per-block scan of chunk partials -> incoming carry for this chunk.
    // Bc is ~1-2 MB total -> L2-resident; chain is <=NC-1 dependent FMAs.
    float accx = 0.f, accy = 0.f;
    {
        const float* Ab = A + b * NC;
        const float* Bb = Bc + (size_t)b * NC * UU + u;
        for (int c = 0; c < chunk; ++c) {
            float a = Ab[c];
            f2 bv = *reinterpret_cast<const f2*>(Bb + (size_t)c * UU);
            accx = fmaf(a, accx, bv.x);
            accy = fmaf(a, accy, bv.y);
        }
    }

    const float* row  = in  + ((size_t)b * TT + (size_t)chunk * CC) * FF;
    float*       orow = out + ((size_t)b * TT + (size_t)chunk * CC) * UU + u;

#pragma unroll 8
    for (int t = 0; t < CC; ++t) {
        f2 xy = *reinterpret_cast<const f2*>(row + (size_t)t * FF);
        f2 z  = *reinterpret_cast<const f2*>(row + (size_t)t * FF + 2 + u);
        accx = fmaf(xy.y, accx, xy.x * z.x);
        accy = fmaf(xy.y, accy, xy.x * z.y);
        f2 o; o.x = accx; o.y = accy;
        __builtin_nontemporal_store(o, reinterpret_cast<f2*>(orow + (size_t)t * UU));
    }
}

extern "C" void kernel_launch(void* const* d_in, const int* in_sizes, int n_in,
                              void* d_out, int out_size, void* d_ws, size_t ws_size,
                              hipStream_t stream) {
    const float* in  = (const float*)d_in[0];
    float*       out = (float*)d_out;
    float*       A   = (float*)d_ws;

    // Prefer NC=64 (1024 blocks, 50% occupancy) if the workspace can hold
    // Bc = BB*NC*UU floats; otherwise fall back to NC=32 (proved to fit).
    const size_t need64 = (size_t)(BB * 64 + BB * 64 * UU) * sizeof(float);
    if (ws_size >= need64) {
        constexpr int NC = 64;
        float* Bc = A + BB * NC;
        k_partial<NC><<<BB * NC * 2, 256, 0, stream>>>(in, A, Bc);
        k_final<NC><<<BB * NC * 2, 256, 0, stream>>>(in, A, Bc, out);
    } else {
        constexpr int NC = 32;
        float* Bc = A + BB * NC;
        k_partial<NC><<<BB * NC * 2, 256, 0, stream>>>(in, A, Bc);
        k_final<NC><<<BB * NC * 2, 256, 0, stream>>>(in, A, Bc, out);
    }
}